// Round 2
// baseline (67.685 us; speedup 1.0000x reference)
//
#include <hip/hip_runtime.h>

#define NPTS 768
#define TPB  256

// out[a,i] = sum_{b,r,j} rbf(d(a,b))[r]/sqrt(n) * W[r,i,j] * f[b,j]
// One block per output row a. Factor: T[r,j] = sum_b rbf[b,r]*f[b,j]; out = W : T.
// All float I/O is fp32 (reference dtypes).
__global__ __launch_bounds__(TPB) void rbf_conv_kernel(
        const float* __restrict__ feat,   // [768][16] f32
        const float* __restrict__ geom,   // [768][3]  f32
        const float* __restrict__ Wp,     // [8][16][16] f32
        const float* __restrict__ mup,    // [8] f32
        const float* __restrict__ gmp,    // [8] f32
        const int*   __restrict__ nn,     // [1] int32
        float* __restrict__ outp)         // [768][16] f32
{
    // zone: phase1/2 = rbf rows (12 floats / 48 B stride, 2 aligned float4 each)
    //       phase3   = Tp[64][132] f32 partials (33792 B <= 36864 B)
    __shared__ __align__(16) float zone[NPTS * 12];   // 36864 B
    __shared__ float gx[NPTS], gy[NPTS], gz[NPTS];    // 9216 B
    __shared__ float Tred[128];
    __shared__ float Pp[64];

    const int t = threadIdx.x;
    const int a = blockIdx.x;

    // ---- stage geometry -> LDS ----
    for (int b = t; b < NPTS; b += TPB) {
        gx[b] = geom[b * 3 + 0];
        gy[b] = geom[b * 3 + 1];
        gz[b] = geom[b * 3 + 2];
    }
    const float ax = geom[a * 3 + 0];
    const float ay = geom[a * 3 + 1];
    const float az = geom[a * 3 + 2];
    float muv[8], ngv[8];
#pragma unroll
    for (int r = 0; r < 8; ++r) { muv[r] = mup[r]; ngv[r] = -gmp[r]; }
    const float rn = rsqrtf((float)nn[0]);

    __syncthreads();

    // ---- phase 1: rbf[b][0..7] = exp(-gamma*(d-mu)^2) / sqrt(n) ----
    for (int b = t; b < NPTS; b += TPB) {
        float dx = gx[b] - ax, dy = gy[b] - ay, dz = gz[b] - az;
        float d = sqrtf(fmaf(dx, dx, fmaf(dy, dy, fmaf(dz, dz, 1e-9f))));
        float e[8];
#pragma unroll
        for (int r = 0; r < 8; ++r) {
            float t0 = d - muv[r];
            e[r] = __expf(ngv[r] * t0 * t0) * rn;
        }
        *(float4*)(zone + b * 12 + 0) = make_float4(e[0], e[1], e[2], e[3]);
        *(float4*)(zone + b * 12 + 4) = make_float4(e[4], e[5], e[6], e[7]);
    }
    __syncthreads();

    // ---- phase 2: T-partials. thread (g = t>>2, jq = t&3) owns j = jq*4..jq*4+3 ----
    const int jq = t & 3;
    const int g  = t >> 2;
    float acc[8][4];
#pragma unroll
    for (int r = 0; r < 8; ++r)
#pragma unroll
        for (int jj = 0; jj < 4; ++jj) acc[r][jj] = 0.f;

    const float4* feat4 = (const float4*)feat;   // [768][4] float4
#pragma unroll
    for (int k = 0; k < 12; ++k) {
        const int b = g + (k << 6);
        const float4 ra = *(const float4*)(zone + b * 12 + 0);  // rbf r=0..3
        const float4 rb = *(const float4*)(zone + b * 12 + 4);  // rbf r=4..7
        const float4 fv = feat4[b * 4 + jq];                    // f[b][jq*4..+3], coalesced
        float rr[8] = { ra.x, ra.y, ra.z, ra.w, rb.x, rb.y, rb.z, rb.w };
        float fj[4] = { fv.x, fv.y, fv.z, fv.w };
#pragma unroll
        for (int r = 0; r < 8; ++r)
#pragma unroll
            for (int jj = 0; jj < 4; ++jj)
                acc[r][jj] = fmaf(rr[r], fj[jj], acc[r][jj]);
    }
    __syncthreads();   // all zone reads done before overwrite

    // ---- phase 3: partials Tp[g][r*16 + jq*4 + jj], row stride 132 floats ----
    float* Tp = zone;
#pragma unroll
    for (int r = 0; r < 8; ++r) {
        *(float4*)(Tp + g * 132 + r * 16 + jq * 4) =
            make_float4(acc[r][0], acc[r][1], acc[r][2], acc[r][3]);
    }
    __syncthreads();

    // reduce 64 g-partials -> Tred[r*16+j]  (2 waves, 2-way bank aliasing: free)
    if (t < 128) {
        const int r = t >> 4, j = t & 15;
        float s = 0.f;
        const float* base = Tp + r * 16 + j;
        for (int gg = 0; gg < 64; ++gg) s += base[gg * 132];
        Tred[t] = s;
    }
    __syncthreads();

    // epilogue: out[i] = sum_{r,j} W[r,i,j] * T[r,j]
    if (t < 64) {
        const int i = t & 15, q = t >> 4;
        float s = 0.f;
#pragma unroll
        for (int m = 0; m < 32; ++m) {
            const int rj = q * 32 + m;
            const int r = rj >> 4, j = rj & 15;
            s = fmaf(Wp[r * 256 + i * 16 + j], Tred[rj], s);
        }
        Pp[t] = s;
    }
    __syncthreads();

    if (t < 16) {
        const float s = Pp[t] + Pp[t + 16] + Pp[t + 32] + Pp[t + 48];
        outp[a * 16 + t] = s;
    }
}

extern "C" void kernel_launch(void* const* d_in, const int* in_sizes, int n_in,
                              void* d_out, int out_size, void* d_ws, size_t ws_size,
                              hipStream_t stream) {
    const float* feat = (const float*)d_in[0];
    const float* geom = (const float*)d_in[1];
    const float* Wp   = (const float*)d_in[2];
    const float* mup  = (const float*)d_in[3];
    const float* gmp  = (const float*)d_in[4];
    const int*   nn   = (const int*)d_in[5];
    float* outp = (float*)d_out;
    rbf_conv_kernel<<<dim3(NPTS), dim3(TPB), 0, stream>>>(feat, geom, Wp, mup, gmp, nn, outp);
}